// Round 3
// baseline (286.932 us; speedup 1.0000x reference)
//
#include <hip/hip_runtime.h>
#include <stdint.h>

// D3 dispersion on MI355X (gfx950). R20: slim-hybrid — drop the scatter/bucket
// pipeline (48 MB recs round-trip + LDS sort machinery) for direct pair passes
// with global atomics. Dispatches: memset(cnfix 256KB) -> pair_cn_fix (25MB
// read, u32 fixed-point cn atomics, prologue fills f16 rc6pad) -> atom_weights
// (65K atoms: cn->weights, f16 arec pack, zeroes out) -> pair_energy (25MB
// read + L2-resident f16 gathers, fp32 atomics to out).
// R20 theory: iteration = 54 dispatches (fill Dispatch_Id spacing), ~50 are
// harness restore/poison => harness floor ~100us, our budget ~35-40us. Bucket
// path's recs write+2x read (48MB) + scatter LDS sort costs more than the
// global atomics it avoids (2M atomics, ~30/address, L2-side).
// Ledger: R18 burst-write WIN (-8.8us, write-amp real); R19 SBLOCKS 256
// NEUTRAL (run halving re-created partial lines / scatter small). Falsified:
// wave count (R9), coop fusion (R7), per-thread batching (R11), record
// packing (R13), SW pipe (R14), LDS sub-slots/fast-math (R15), block-count
// run-length (R16/R19).
// Reference semantics (R2-R5): fp32 storage; np reference is fp32 with FTZ in
// exp -> exceptional one-hot branch iff every masked gaussian arg < -87.33654.
// cn via u32 fixed-point (2^25): deterministic, per-term err 2^-26, max cn
// ~66 << 2^32/2^25=128 headroom.

typedef unsigned short u16;
#define MAXZ 95
#define NREF 5
#define EXC_CUT -87.33654f
#define RC_TOTAL (MAXZ * MAXZ * 32)
#define CN_SCALE 33554432.0f          // 2^25
#define CN_INV   2.9802322387695312e-8f  // 2^-25

__device__ __forceinline__ float h2f(u16 h) {
    union { _Float16 h; u16 u; } v; v.u = h; return (float)v.h;
}
__device__ __forceinline__ u16 f2h(float f) {
    union { _Float16 h; u16 u; } v; v.h = (_Float16)f; return v.u;
}

__device__ __forceinline__ float switch_fn(float d) {
    if (d < 10.0f) return 1.0f;
    float x = (12.0f - d) * 0.5f;
    return ((6.0f * x - 15.0f) * x + 10.0f) * x * x * x;
}

__device__ __forceinline__ void calc_weights(const float* __restrict__ rcn_z,
                                             float cni, float* __restrict__ w) {
    float r[NREF], arg[NREF];
    float rmax = -1e30f, marg = -1e30f;
#pragma unroll
    for (int a = 0; a < NREF; a++) {
        r[a] = rcn_z[a];
        rmax = fmaxf(rmax, r[a]);
        float dc = r[a] - cni;
        arg[a] = (-4.0f * dc) * dc;
        if (r[a] >= 0.0f) marg = fmaxf(marg, arg[a]);
    }
    if (marg < EXC_CUT) {
#pragma unroll
        for (int a = 0; a < NREF; a++) w[a] = (r[a] == rmax) ? 1.0f : 0.0f;
    } else {
        float g[NREF], norm = 0.0f;
#pragma unroll
        for (int a = 0; a < NREF; a++) {
            float e = (r[a] >= 0.0f) ? expf(arg[a]) : 0.0f;
            g[a] = e;
            norm += e;
        }
        float inv = 1.0f / fmaxf(norm, 1e-30f);
#pragma unroll
        for (int a = 0; a < NREF; a++) w[a] = g[a] * inv;
    }
}

// ---------------------------------------------------------------------------
// Pass 1: coordination numbers via u32 fixed-point atomics (deterministic).
// Prologue fills f16 rc6pad (read only by pass 3 -> cross-kernel ordering OK).
__global__ __launch_bounds__(1024) void pair_cn_fix(const float* __restrict__ dist,
                                                    const int* __restrict__ idx_i,
                                                    const int* __restrict__ idx_j,
                                                    const int* __restrict__ Z,
                                                    const float* __restrict__ rcov,
                                                    const float* __restrict__ rc6,
                                                    u16* __restrict__ rc6pad,
                                                    uint32_t* __restrict__ cnfix,
                                                    int n_pairs) {
    int g = blockIdx.x * 1024 + (int)threadIdx.x;
    int T = gridDim.x * 1024;
    for (int id = g; id < RC_TOTAL; id += T) {
        int tile = id >> 5, slot = id & 31;
        rc6pad[id] = (slot < 25) ? f2h(rc6[(size_t)tile * 25 + slot]) : (u16)0;
    }

    for (int q0 = g * 4; q0 < n_pairs; q0 += T * 4) {
        int m = min(4, n_pairs - q0);
        float d4[4]; int i4[4], j4[4];
        if (m == 4) {
            float4 dv = *(const float4*)(dist + q0);
            int4 iv = *(const int4*)(idx_i + q0);
            int4 jv = *(const int4*)(idx_j + q0);
            d4[0] = dv.x; d4[1] = dv.y; d4[2] = dv.z; d4[3] = dv.w;
            i4[0] = iv.x; i4[1] = iv.y; i4[2] = iv.z; i4[3] = iv.w;
            j4[0] = jv.x; j4[1] = jv.y; j4[2] = jv.z; j4[3] = jv.w;
        } else {
            for (int s = 0; s < m; s++) {
                d4[s] = dist[q0 + s]; i4[s] = idx_i[q0 + s]; j4[s] = idx_j[q0 + s];
            }
        }
#pragma unroll
        for (int s = 0; s < 4; s++) {
            if (s >= m) continue;
            float d = d4[s];
            if (d >= 12.0f) continue;
            float rij = rcov[Z[i4[s]]] + rcov[Z[j4[s]]];
            float sw = switch_fn(d);
            float c = sw / (1.0f + expf(-16.0f * (rij / d - 1.0f)));
            atomicAdd(&cnfix[i4[s]], __float2uint_rn(c * CN_SCALE));
        }
    }
}

// ---------------------------------------------------------------------------
// Pass 2: per-atom weights -> packed f16 arec {w0..w4, r2r4, z}; zeroes out.
__global__ __launch_bounds__(256) void atom_weights(const uint32_t* __restrict__ cnfix,
                                                    const int* __restrict__ Z,
                                                    const float* __restrict__ rcn,
                                                    const float* __restrict__ r2r4,
                                                    uint4* __restrict__ arec_h,
                                                    float* __restrict__ eout,
                                                    int n_atoms) {
    int i = blockIdx.x * 256 + (int)threadIdx.x;
    if (i >= n_atoms) return;
    float cni = (float)cnfix[i] * CN_INV;
    int z = Z[i];
    float w[NREF];
    calc_weights(rcn + (size_t)z * NREF, cni, w);
    uint4 pk;
    pk.x = (uint32_t)f2h(w[0]) | ((uint32_t)f2h(w[1]) << 16);
    pk.y = (uint32_t)f2h(w[2]) | ((uint32_t)f2h(w[3]) << 16);
    pk.z = (uint32_t)f2h(w[4]) | ((uint32_t)f2h(r2r4[z]) << 16);
    pk.w = (uint32_t)z;
    arec_h[i] = pk;
    eout[i] = 0.0f;
}

// ---------------------------------------------------------------------------
// Pass 3: per-pair energy; both weight records gathered from L2-resident arec;
// 64B f16 rc6 tile gather; fp32 atomic into out[i].
__global__ __launch_bounds__(256) void pair_energy(const float* __restrict__ dist,
                                                   const int* __restrict__ idx_i,
                                                   const int* __restrict__ idx_j,
                                                   const uint4* __restrict__ arec_h,
                                                   const u16* __restrict__ rc6pad,
                                                   const float* __restrict__ s6p,
                                                   const float* __restrict__ s8p,
                                                   const float* __restrict__ a1p,
                                                   const float* __restrict__ a2p,
                                                   float* __restrict__ eout,
                                                   int n_pairs) {
    float s6 = s6p[0], s8 = s8p[0], a1 = a1p[0], a2 = a2p[0];
    int g = blockIdx.x * 256 + (int)threadIdx.x;
    int T = gridDim.x * 256;
    for (int q0 = g * 4; q0 < n_pairs; q0 += T * 4) {
        int m = min(4, n_pairs - q0);
        float d4[4]; int i4[4], j4[4];
        if (m == 4) {
            float4 dv = *(const float4*)(dist + q0);
            int4 iv = *(const int4*)(idx_i + q0);
            int4 jv = *(const int4*)(idx_j + q0);
            d4[0] = dv.x; d4[1] = dv.y; d4[2] = dv.z; d4[3] = dv.w;
            i4[0] = iv.x; i4[1] = iv.y; i4[2] = iv.z; i4[3] = iv.w;
            j4[0] = jv.x; j4[1] = jv.y; j4[2] = jv.z; j4[3] = jv.w;
        } else {
            for (int s = 0; s < m; s++) {
                d4[s] = dist[q0 + s]; i4[s] = idx_i[q0 + s]; j4[s] = idx_j[q0 + s];
            }
        }
#pragma unroll
        for (int s = 0; s < 4; s++) {
            if (s >= m) continue;
            float d = d4[s];
            if (d >= 12.0f) continue;
            uint4 pi = arec_h[i4[s]];
            uint4 pj = arec_h[j4[s]];
            int zi = (int)pi.w;
            int zj = (int)pj.w;
            const uint4* T4 = (const uint4*)(rc6pad + (size_t)(zi * MAXZ + zj) * 32);
            uint4 t0 = T4[0], t1 = T4[1], t2 = T4[2];
            uint32_t t3 = ((const uint32_t*)T4)[12];

            float wi[NREF] = {h2f(pi.x & 0xFFFFu), h2f(pi.x >> 16),
                              h2f(pi.y & 0xFFFFu), h2f(pi.y >> 16),
                              h2f(pi.z & 0xFFFFu)};
            float wj[NREF] = {h2f(pj.x & 0xFFFFu), h2f(pj.x >> 16),
                              h2f(pj.y & 0xFFFFu), h2f(pj.y >> 16),
                              h2f(pj.z & 0xFFFFu)};
            float r2r4i = h2f(pi.z >> 16);
            float r2r4j = h2f(pj.z >> 16);

            float tt[25];
            uint32_t tw[12] = {t0.x, t0.y, t0.z, t0.w, t1.x, t1.y, t1.z, t1.w,
                               t2.x, t2.y, t2.z, t2.w};
#pragma unroll
            for (int k2 = 0; k2 < 12; k2++) {
                tt[2 * k2]     = h2f((u16)(tw[k2] & 0xFFFFu));
                tt[2 * k2 + 1] = h2f((u16)(tw[k2] >> 16));
            }
            tt[24] = h2f((u16)(t3 & 0xFFFFu));

            float c6 = 0.0f;
#pragma unroll
            for (int a = 0; a < NREF; a++) {
                float ss = 0.0f;
#pragma unroll
                for (int bb = 0; bb < NREF; bb++) ss = fmaf(wj[bb], tt[a * NREF + bb], ss);
                c6 = fmaf(wi[a], ss, c6);
            }

            float qq = 3.0f * r2r4i * r2r4j;
            float rr = a1 * sqrtf(qq) + a2;
            float d2 = d * d;
            float d6 = d2 * d2 * d2;
            float d8 = d6 * d2;
            float rr2 = rr * rr;
            float rr6 = rr2 * rr2 * rr2;
            float rr8 = rr6 * rr2;
            float sw = switch_fn(d);

            float e = -0.5f * (s6 * c6 / (d6 + rr6) + s8 * qq * c6 / (d8 + rr8)) * sw;
            atomicAdd(&eout[i4[s]], e);
        }
    }
}

// ---------------------------------------------------------------------------
// Slim fallback (tiny workspace): R5-style global-atomic fp32 path.
__global__ __launch_bounds__(256) void pair_cn_slim(const float* __restrict__ dist,
                                                    const float* __restrict__ rcov,
                                                    const int* __restrict__ Z,
                                                    const int* __restrict__ idx_i,
                                                    const int* __restrict__ idx_j,
                                                    float* __restrict__ cn,
                                                    int n_pairs) {
    int p = blockIdx.x * blockDim.x + threadIdx.x;
    if (p >= n_pairs) return;
    float d = dist[p];
    if (d >= 12.0f) return;
    float rij = rcov[Z[idx_i[p]]] + rcov[Z[idx_j[p]]];
    float sw = switch_fn(d);
    atomicAdd(&cn[idx_i[p]], sw / (1.0f + expf(-16.0f * (rij / d - 1.0f))));
}

__global__ __launch_bounds__(256) void pair_energy_slim(const float* __restrict__ dist,
                                                        const int* __restrict__ Z,
                                                        const int* __restrict__ idx_i,
                                                        const int* __restrict__ idx_j,
                                                        const float* __restrict__ cn,
                                                        const float* __restrict__ rcn,
                                                        const float* __restrict__ r2r4,
                                                        const float* __restrict__ rc6,
                                                        const float* __restrict__ s6p,
                                                        const float* __restrict__ s8p,
                                                        const float* __restrict__ a1p,
                                                        const float* __restrict__ a2p,
                                                        float* __restrict__ eout,
                                                        int n_pairs) {
    int p = blockIdx.x * blockDim.x + threadIdx.x;
    if (p >= n_pairs) return;
    float d = dist[p];
    if (d >= 12.0f) return;
    int i = idx_i[p], j = idx_j[p];
    int zi = Z[i], zj = Z[j];
    float wi[NREF], wj[NREF];
    calc_weights(rcn + (size_t)zi * NREF, cn[i], wi);
    calc_weights(rcn + (size_t)zj * NREF, cn[j], wj);
    const float* T = rc6 + (size_t)(zi * MAXZ + zj) * 25;
    float c6 = 0.0f;
#pragma unroll
    for (int a = 0; a < NREF; a++) {
        float s = 0.0f;
#pragma unroll
        for (int bb = 0; bb < NREF; bb++) s = fmaf(wj[bb], T[a * NREF + bb], s);
        c6 = fmaf(wi[a], s, c6);
    }
    float qq = 3.0f * r2r4[zi] * r2r4[zj];
    float rr = a1p[0] * sqrtf(qq) + a2p[0];
    float d2 = d * d;
    float d6 = d2 * d2 * d2;
    float d8 = d6 * d2;
    float rr2 = rr * rr;
    float rr6 = rr2 * rr2 * rr2;
    float rr8 = rr6 * rr2;
    float sw = switch_fn(d);
    float e = -0.5f * (s6p[0] * c6 / (d6 + rr6) + s8p[0] * qq * c6 / (d8 + rr8)) * sw;
    atomicAdd(&eout[i], e);
}

// ---------------------------------------------------------------------------
extern "C" void kernel_launch(void* const* d_in, const int* in_sizes, int n_in,
                              void* d_out, int out_size, void* d_ws, size_t ws_size,
                              hipStream_t stream) {
    const float* dist = (const float*)d_in[0];
    const float* rcov = (const float*)d_in[1];
    const float* rcn  = (const float*)d_in[2];
    const float* rc6  = (const float*)d_in[3];
    const float* r2r4 = (const float*)d_in[4];
    const float* s6p  = (const float*)d_in[5];
    const float* s8p  = (const float*)d_in[6];
    const float* a1p  = (const float*)d_in[7];
    const float* a2p  = (const float*)d_in[8];
    const int* Z    = (const int*)d_in[9];
    const int* idxi = (const int*)d_in[10];
    const int* idxj = (const int*)d_in[11];
    float* out = (float*)d_out;

    int n_pairs = in_sizes[0];
    int n_atoms = in_sizes[9];

    char* ws = (char*)d_ws;
    size_t o_cnfix = 0;                                        // n_atoms u32
    size_t o_arec  = ((size_t)n_atoms * 4 + 255) & ~(size_t)255;
    size_t o_rc6   = (o_arec + (size_t)n_atoms * 16 + 63) & ~(size_t)63;
    size_t need    = o_rc6 + (size_t)RC_TOTAL * 2;

    uint32_t* cnfix = (uint32_t*)(ws + o_cnfix);
    uint4* arec_h = (uint4*)(ws + o_arec);
    u16*   rcpad  = (u16*)(ws + o_rc6);

    if (ws_size >= need && n_atoms <= 65536) {
        hipMemsetAsync(cnfix, 0, (size_t)n_atoms * 4, stream);
        pair_cn_fix<<<512, 1024, 0, stream>>>(dist, idxi, idxj, Z, rcov, rc6,
                                              rcpad, cnfix, n_pairs);
        atom_weights<<<(n_atoms + 255) / 256, 256, 0, stream>>>(cnfix, Z, rcn, r2r4,
                                                                arec_h, out, n_atoms);
        int egrid = min((n_pairs / 4 + 255) / 256 + 1, 4096);
        pair_energy<<<egrid, 256, 0, stream>>>(dist, idxi, idxj, arec_h, rcpad,
                                               s6p, s8p, a1p, a2p, out, n_pairs);
    } else {
        int pgrid = (n_pairs + 255) / 256;
        float* cn = (float*)(ws + 4096);         // small scratch for cn
        hipMemsetAsync(out, 0, (size_t)n_atoms * 4, stream);
        hipMemsetAsync(cn, 0, (size_t)n_atoms * 4, stream);
        pair_cn_slim<<<pgrid, 256, 0, stream>>>(dist, rcov, Z, idxi, idxj, cn, n_pairs);
        pair_energy_slim<<<pgrid, 256, 0, stream>>>(dist, Z, idxi, idxj, cn, rcn, r2r4,
                                                    rc6, s6p, s8p, a1p, a2p, out, n_pairs);
    }
}

// Round 4
// 260.436 us; speedup vs baseline: 1.1017x; 1.1017x over previous
//
#include <hip/hip_runtime.h>
#include <hip/hip_cooperative_groups.h>
#include <stdint.h>

// D3 dispersion on MI355X (gfx950). R21: revert to R18 bucket pipeline (best
// measured, 139.0us) + fuse cn_weights/energy into ONE cooperative kernel
// (grid.sync between phases) so each block's phase-2 recs re-read hits L2/L3
// instead of HBM, and one launch gap disappears.
// Pipeline: scatter (128x1024, 16K-pair LDS bucket-sort tiles -> rank-ordered
// burst writes; prologue fills rcovA+f16 rc6pad) -> cooperative cn+energy
// (1024x256: phase1 CN via LDS accum + f16 weight pack -> grid.sync ->
// phase2 energy, f16 arec/table gathers, LDS accum). Zero global fp32 atomics.
// Ledger: R18 burst-write WIN (-8.8us, write-amp real). R19 SBLOCKS=256
// NEUTRAL (run halving re-created partial lines). R20 slim-hybrid REGRESSION
// (287us): 2M random global fp32 atomics + unpipelined gathers = 117us
// pair_energy @ 8.8% HBM / 57% occ -> "zero global fp32 atomics" invariant is
// load-bearing; recs round-trip is cheaper than the atomics it avoids.
// Falsified earlier: wave count (R9), coop fusion of scatter (R7), per-thread
// batching (R11), record packing (R13), SW pipe (R14), LDS sub-slots (R15),
// block-count run-length (R16/R19).
// Harness floor: iteration = 54 dispatches, ~50 harness (~95-100us incl 45us
// 268MB poison fill); our 4 dispatches ~40us.
// Reference semantics (R2-R5): fp32 storage; np reference is fp32 with FTZ in
// exp -> exceptional one-hot branch iff every masked gaussian arg < -87.33654.

namespace cg = cooperative_groups;

typedef unsigned short u16;
#define MAXZ 95
#define NREF 5
#define EXC_CUT -87.33654f
#define NB    1024     // buckets
#define BSH   6        // log2 atoms per bucket
#define BSZ   64       // atoms per bucket
#define CAPSH 12       // bucket capacity 4096 (mean ~1865, sigma ~43)
#define SBLOCKS 128    // scatter blocks (R18 optimum; full 16K tiles)
#define TILE  16384    // pairs staged+sorted per LDS tile (128 KB)
#define RC_TOTAL (MAXZ * MAXZ * 32)

__device__ __forceinline__ float h2f(u16 h) {
    union { _Float16 h; u16 u; } v; v.u = h; return (float)v.h;
}
__device__ __forceinline__ u16 f2h(float f) {
    union { _Float16 h; u16 u; } v; v.h = (_Float16)f; return v.u;
}

__device__ __forceinline__ float switch_fn(float d) {
    if (d < 10.0f) return 1.0f;
    float x = (12.0f - d) * 0.5f;
    return ((6.0f * x - 15.0f) * x + 10.0f) * x * x * x;
}

__device__ __forceinline__ void calc_weights(const float* __restrict__ rcn_z,
                                             float cni, float* __restrict__ w) {
    float r[NREF], arg[NREF];
    float rmax = -1e30f, marg = -1e30f;
#pragma unroll
    for (int a = 0; a < NREF; a++) {
        r[a] = rcn_z[a];
        rmax = fmaxf(rmax, r[a]);
        float dc = r[a] - cni;
        arg[a] = (-4.0f * dc) * dc;
        if (r[a] >= 0.0f) marg = fmaxf(marg, arg[a]);
    }
    if (marg < EXC_CUT) {
#pragma unroll
        for (int a = 0; a < NREF; a++) w[a] = (r[a] == rmax) ? 1.0f : 0.0f;
    } else {
        float g[NREF], norm = 0.0f;
#pragma unroll
        for (int a = 0; a < NREF; a++) {
            float e = (r[a] >= 0.0f) ? expf(arg[a]) : 0.0f;
            g[a] = e;
            norm += e;
        }
        float inv = 1.0f / fmaxf(norm, 1e-30f);
#pragma unroll
        for (int a = 0; a < NREF; a++) w[a] = g[a] * inv;
    }
}

// ---------------------------------------------------------------------------
// Scatter pairs into fixed-stride buckets; prologue fills rcovA + f16 rc6pad.
// Per 16K-pair tile: load once into regs -> LDS hist -> hierarchical shfl
// scan (2 barriers) -> LDS bucket-sort -> rank-ordered burst write.
// Record: {d_fp32, j | il<<16}; bucket id rides in bits 22..31 while staged.
__global__ __launch_bounds__(1024) void scatter_pairs(const float* __restrict__ dist,
                                                      const int* __restrict__ idx_i,
                                                      const int* __restrict__ idx_j,
                                                      const int* __restrict__ Z,
                                                      const float* __restrict__ rcov,
                                                      const float* __restrict__ rc6,
                                                      float* __restrict__ rcovA,
                                                      u16* __restrict__ rc6pad,
                                                      uint32_t* __restrict__ bcount,
                                                      uint2* __restrict__ recs,
                                                      int n_pairs, int n_atoms,
                                                      int chunk) {
    __shared__ uint2 stage[TILE];          // 128 KB, bucket-sorted records
    __shared__ uint32_t hist[NB];          // per-tile bucket counts
    __shared__ uint32_t startb[NB];        // exclusive scan of hist
    __shared__ uint32_t cur[NB];           // scatter cursor
    __shared__ uint32_t res[NB];           // global base per bucket (this tile)
    __shared__ uint32_t wsum[16];          // per-wave scan partials

    int tid = (int)threadIdx.x;
    int g = blockIdx.x * 1024 + tid;
    int T = gridDim.x * 1024;
    for (int i = g; i < n_atoms; i += T) rcovA[i] = rcov[Z[i]];
    for (int id = g; id < RC_TOTAL; id += T) {
        int tile = id >> 5, slot = id & 31;
        rc6pad[id] = (slot < 25) ? f2h(rc6[(size_t)tile * 25 + slot]) : (u16)0;
    }

    int lo = blockIdx.x * chunk;
    int hi = min(lo + chunk, n_pairs);

    for (int t0 = lo; t0 < hi; t0 += TILE) {
        int tend = min(t0 + TILE, hi);
        hist[tid] = 0;
        __syncthreads();

        // load tile once (4-wide), filter d<12, histogram; hold recs in regs
        uint32_t rx[16], ry[16], vm = 0;
#pragma unroll
        for (int it = 0; it < 4; it++) {
            int q0 = t0 + tid * 4 + it * 4096;
            int m = (q0 < tend) ? min(4, tend - q0) : 0;
            float d4[4]; int i4[4], j4[4];
            if (m == 4) {
                float4 dv = *(const float4*)(dist + q0);
                int4 iv = *(const int4*)(idx_i + q0);
                int4 jv = *(const int4*)(idx_j + q0);
                d4[0] = dv.x; d4[1] = dv.y; d4[2] = dv.z; d4[3] = dv.w;
                i4[0] = iv.x; i4[1] = iv.y; i4[2] = iv.z; i4[3] = iv.w;
                j4[0] = jv.x; j4[1] = jv.y; j4[2] = jv.z; j4[3] = jv.w;
            } else {
                for (int s = 0; s < m; s++) {
                    d4[s] = dist[q0 + s]; i4[s] = idx_i[q0 + s]; j4[s] = idx_j[q0 + s];
                }
            }
#pragma unroll
            for (int s = 0; s < 4; s++) {
                int k = it * 4 + s;
                rx[k] = 0u; ry[k] = 0u;
                if (s < m && d4[s] < 12.0f) {
                    uint32_t i = (uint32_t)i4[s];
                    uint32_t b = i >> BSH;
                    rx[k] = __float_as_uint(d4[s]);
                    ry[k] = ((uint32_t)j4[s] & 0xFFFFu) |
                            ((i & (BSZ - 1u)) << 16) | (b << 22);
                    vm |= (1u << k);
                    atomicAdd(&hist[b], 1u);
                }
            }
        }
        __syncthreads();

        // hierarchical exclusive scan of hist -> startb (2 barriers, shfl)
        {
            uint32_t h = hist[tid];
            int lane = tid & 63, w = tid >> 6;
            uint32_t inc = h;
#pragma unroll
            for (int off = 1; off < 64; off <<= 1) {
                uint32_t v = __shfl_up(inc, off, 64);
                if (lane >= off) inc += v;
            }
            if (lane == 63) wsum[w] = inc;
            __syncthreads();
            if (tid < 16) {
                uint32_t v = wsum[tid];
                uint32_t s = v;
#pragma unroll
                for (int off = 1; off < 16; off <<= 1) {
                    uint32_t u = __shfl_up(s, off, 64);
                    if (tid >= off) s += u;
                }
                wsum[tid] = s - v;         // exclusive wave base
            }
            __syncthreads();
            uint32_t sb = (inc - h) + wsum[w];
            startb[tid] = sb;
            cur[tid] = sb;                 // becomes scatter cursor
            // global reservation for this tile's runs
            res[tid] = h ? atomicAdd(&bcount[tid], h) : 0u;
        }
        __syncthreads();

        // bucket-sort records into LDS
#pragma unroll
        for (int k = 0; k < 16; k++) {
            if (vm & (1u << k)) {
                uint32_t b = ry[k] >> 22;
                uint32_t pos = atomicAdd(&cur[b], 1u);
                stage[pos] = make_uint2(rx[k], ry[k]);
            }
        }
        __syncthreads();

        // burst write: within each run, consecutive lanes -> consecutive addrs
        uint32_t total = startb[NB - 1] + hist[NB - 1];
        for (uint32_t t = (uint32_t)tid; t < total; t += 1024u) {
            uint2 r = stage[t];
            uint32_t b = r.y >> 22;
            uint32_t gpos = res[b] + (t - startb[b]);
            if (gpos < (1u << CAPSH))
                recs[((size_t)b << CAPSH) + gpos] =
                    make_uint2(r.x, r.y & 0x3FFFFFu);
        }
        __syncthreads();
    }
}

// ---------------------------------------------------------------------------
// Phase bodies shared by the fused cooperative kernel and the fallback pair.

__device__ __forceinline__ void cn_phase(const uint2* __restrict__ recs,
                                         const uint32_t* __restrict__ bcount,
                                         const float* __restrict__ rcovA,
                                         const int* __restrict__ Z,
                                         const float* __restrict__ rcn,
                                         const float* __restrict__ r2r4,
                                         uint4* __restrict__ arec_h,
                                         int n_atoms,
                                         float* __restrict__ lrc,
                                         float* __restrict__ acc) {
    int b = blockIdx.x;
    int base = b << BSH;
    if (threadIdx.x < BSZ) {
        int i = base + (int)threadIdx.x;
        lrc[threadIdx.x] = (i < n_atoms) ? rcovA[i] : 0.0f;
        acc[threadIdx.x] = 0.0f;
    }
    __syncthreads();
    uint32_t n = min(bcount[b], 1u << CAPSH);
    const uint2* r0 = recs + ((size_t)b << CAPSH);
    if (n) {
        uint32_t nm1 = n - 1;
        uint32_t k = threadIdx.x;
        uint2 recA = r0[min(k, nm1)];
        uint2 recB = r0[min(k + 256, nm1)];
        float rjA = rcovA[recA.y & 0xFFFF];
        for (; k < n; k += 256) {
            uint2 recC = r0[min(k + 512, nm1)];
            float rjB = rcovA[recB.y & 0xFFFF];
            float d = __uint_as_float(recA.x);
            int il = (recA.y >> 16) & (BSZ - 1);
            float rij = lrc[il] + rjA;
            float sw = switch_fn(d);
            atomicAdd(&acc[il], sw / (1.0f + expf(-16.0f * (rij / d - 1.0f))));
            recA = recB; recB = recC; rjA = rjB;
        }
    }
    __syncthreads();
    if (threadIdx.x < BSZ) {
        int i = base + (int)threadIdx.x;
        if (i < n_atoms) {
            int z = Z[i];
            float w[NREF];
            calc_weights(rcn + (size_t)z * NREF, acc[threadIdx.x], w);
            uint4 pk;
            pk.x = (uint32_t)f2h(w[0]) | ((uint32_t)f2h(w[1]) << 16);
            pk.y = (uint32_t)f2h(w[2]) | ((uint32_t)f2h(w[3]) << 16);
            pk.z = (uint32_t)f2h(w[4]) | ((uint32_t)f2h(r2r4[z]) << 16);
            pk.w = (uint32_t)z;
            arec_h[i] = pk;
        }
    }
}

__device__ __forceinline__ void energy_phase(const uint2* __restrict__ recs,
                                             const uint32_t* __restrict__ bcount,
                                             const uint4* __restrict__ arec_h,
                                             const u16* __restrict__ rc6pad,
                                             float s6, float s8, float a1, float a2,
                                             float* __restrict__ eout,
                                             int n_atoms,
                                             float4* __restrict__ la0,
                                             float4* __restrict__ la1,
                                             float* __restrict__ acc) {
    int b = blockIdx.x;
    int base = b << BSH;
    if (threadIdx.x < BSZ) {
        int i = min(base + (int)threadIdx.x, n_atoms - 1);
        uint4 pk = arec_h[i];
        la0[threadIdx.x] = make_float4(h2f(pk.x & 0xFFFFu), h2f(pk.x >> 16),
                                       h2f(pk.y & 0xFFFFu), h2f(pk.y >> 16));
        la1[threadIdx.x] = make_float4(h2f(pk.z & 0xFFFFu), h2f(pk.z >> 16),
                                       __int_as_float((int)pk.w), 0.0f);
        acc[threadIdx.x] = 0.0f;
    }
    __syncthreads();
    uint32_t n = min(bcount[b], 1u << CAPSH);
    const uint2* r0 = recs + ((size_t)b << CAPSH);
    if (n) {
        uint32_t nm1 = n - 1;
        uint32_t k = threadIdx.x;
        uint2 recA = r0[min(k, nm1)];
        uint2 recB = r0[min(k + 256, nm1)];
        uint4 pjA = arec_h[recA.y & 0xFFFFu];
        for (; k < n; k += 256) {
            uint2 recC = r0[min(k + 512, nm1)];
            uint4 pjB = arec_h[recB.y & 0xFFFFu];

            int il = (recA.y >> 16) & (BSZ - 1);
            float4 ai1 = la1[il];
            int zi = __float_as_int(ai1.z);
            int zj = (int)pjA.w;
            const uint4* T4 = (const uint4*)(rc6pad + (size_t)(zi * MAXZ + zj) * 32);
            uint4 t0 = T4[0], t1 = T4[1], t2 = T4[2];
            uint32_t t3 = ((const uint32_t*)T4)[12];

            float d = __uint_as_float(recA.x);
            float4 ai0 = la0[il];
            float wi[NREF] = {ai0.x, ai0.y, ai0.z, ai0.w, ai1.x};
            float wj[NREF] = {h2f(pjA.x & 0xFFFFu), h2f(pjA.x >> 16),
                              h2f(pjA.y & 0xFFFFu), h2f(pjA.y >> 16),
                              h2f(pjA.z & 0xFFFFu)};
            float r2r4j = h2f(pjA.z >> 16);

            float tt[25];
            uint32_t tw[12] = {t0.x, t0.y, t0.z, t0.w, t1.x, t1.y, t1.z, t1.w,
                               t2.x, t2.y, t2.z, t2.w};
#pragma unroll
            for (int k2 = 0; k2 < 12; k2++) {
                tt[2 * k2]     = h2f((u16)(tw[k2] & 0xFFFFu));
                tt[2 * k2 + 1] = h2f((u16)(tw[k2] >> 16));
            }
            tt[24] = h2f((u16)(t3 & 0xFFFFu));

            float c6 = 0.0f;
#pragma unroll
            for (int a = 0; a < NREF; a++) {
                float ss = 0.0f;
#pragma unroll
                for (int bb = 0; bb < NREF; bb++) ss = fmaf(wj[bb], tt[a * NREF + bb], ss);
                c6 = fmaf(wi[a], ss, c6);
            }

            float qq = 3.0f * ai1.y * r2r4j;
            float rr = a1 * sqrtf(qq) + a2;
            float d2 = d * d;
            float d6 = d2 * d2 * d2;
            float d8 = d6 * d2;
            float rr2 = rr * rr;
            float rr6 = rr2 * rr2 * rr2;
            float rr8 = rr6 * rr2;
            float sw = switch_fn(d);

            float e = -0.5f * (s6 * c6 / (d6 + rr6) + s8 * qq * c6 / (d8 + rr8)) * sw;
            atomicAdd(&acc[il], e);

            recA = recB; recB = recC; pjA = pjB;
        }
    }
    __syncthreads();
    if (threadIdx.x < BSZ) {
        int i = base + (int)threadIdx.x;
        if (i < n_atoms) eout[i] = acc[threadIdx.x];
    }
}

// ---------------------------------------------------------------------------
// Fused cooperative kernel: phase1 cn+weights -> grid.sync -> phase2 energy.
// Same-block recs re-read in phase2 hits L2/L3 (written us earlier by phase1's
// own reads keeping lines warm); arec round-trip stays cached.
__global__ __launch_bounds__(256) void cn_energy_fused(const uint2* __restrict__ recs,
                                                       const uint32_t* __restrict__ bcount,
                                                       const float* __restrict__ rcovA,
                                                       const int* __restrict__ Z,
                                                       const float* __restrict__ rcn,
                                                       const float* __restrict__ r2r4,
                                                       uint4* __restrict__ arec_h,
                                                       const u16* __restrict__ rc6pad,
                                                       const float* __restrict__ s6p,
                                                       const float* __restrict__ s8p,
                                                       const float* __restrict__ a1p,
                                                       const float* __restrict__ a2p,
                                                       float* __restrict__ eout,
                                                       int n_atoms) {
    __shared__ float lrc[BSZ];
    __shared__ float accc[BSZ];
    __shared__ float4 la0[BSZ];
    __shared__ float4 la1[BSZ];
    __shared__ float acce[BSZ];

    cn_phase(recs, bcount, rcovA, Z, rcn, r2r4, arec_h, n_atoms, lrc, accc);

    cg::this_grid().sync();

    float s6 = s6p[0], s8 = s8p[0], a1 = a1p[0], a2 = a2p[0];
    energy_phase(recs, bcount, arec_h, rc6pad, s6, s8, a1, a2, eout, n_atoms,
                 la0, la1, acce);
}

// Fallback standalone pair (identical numerics).
__global__ __launch_bounds__(256) void cn_weights_bucket(const uint2* __restrict__ recs,
                                                         const uint32_t* __restrict__ bcount,
                                                         const float* __restrict__ rcovA,
                                                         const int* __restrict__ Z,
                                                         const float* __restrict__ rcn,
                                                         const float* __restrict__ r2r4,
                                                         uint4* __restrict__ arec_h,
                                                         int n_atoms) {
    __shared__ float lrc[BSZ];
    __shared__ float acc[BSZ];
    cn_phase(recs, bcount, rcovA, Z, rcn, r2r4, arec_h, n_atoms, lrc, acc);
}

__global__ __launch_bounds__(256) void energy_bucket(const uint2* __restrict__ recs,
                                                     const uint32_t* __restrict__ bcount,
                                                     const uint4* __restrict__ arec_h,
                                                     const u16* __restrict__ rc6pad,
                                                     const float* __restrict__ s6p,
                                                     const float* __restrict__ s8p,
                                                     const float* __restrict__ a1p,
                                                     const float* __restrict__ a2p,
                                                     float* __restrict__ eout,
                                                     int n_atoms) {
    __shared__ float4 la0[BSZ];
    __shared__ float4 la1[BSZ];
    __shared__ float acc[BSZ];
    float s6 = s6p[0], s8 = s8p[0], a1 = a1p[0], a2 = a2p[0];
    energy_phase(recs, bcount, arec_h, rc6pad, s6, s8, a1, a2, eout, n_atoms,
                 la0, la1, acc);
}

// ---------------------------------------------------------------------------
// Slim fallback (small workspace): R5-style global-atomic fp32 path.
__global__ __launch_bounds__(256) void pair_cn_slim(const float* __restrict__ dist,
                                                    const float* __restrict__ rcov,
                                                    const int* __restrict__ Z,
                                                    const int* __restrict__ idx_i,
                                                    const int* __restrict__ idx_j,
                                                    float* __restrict__ cn,
                                                    int n_pairs) {
    int p = blockIdx.x * blockDim.x + threadIdx.x;
    if (p >= n_pairs) return;
    float d = dist[p];
    if (d >= 12.0f) return;
    float rij = rcov[Z[idx_i[p]]] + rcov[Z[idx_j[p]]];
    float sw = switch_fn(d);
    atomicAdd(&cn[idx_i[p]], sw / (1.0f + expf(-16.0f * (rij / d - 1.0f))));
}

__global__ __launch_bounds__(256) void pair_energy_slim(const float* __restrict__ dist,
                                                        const int* __restrict__ Z,
                                                        const int* __restrict__ idx_i,
                                                        const int* __restrict__ idx_j,
                                                        const float* __restrict__ cn,
                                                        const float* __restrict__ rcn,
                                                        const float* __restrict__ r2r4,
                                                        const float* __restrict__ rc6,
                                                        const float* __restrict__ s6p,
                                                        const float* __restrict__ s8p,
                                                        const float* __restrict__ a1p,
                                                        const float* __restrict__ a2p,
                                                        float* __restrict__ eout,
                                                        int n_pairs) {
    int p = blockIdx.x * blockDim.x + threadIdx.x;
    if (p >= n_pairs) return;
    float d = dist[p];
    if (d >= 12.0f) return;
    int i = idx_i[p], j = idx_j[p];
    int zi = Z[i], zj = Z[j];
    float wi[NREF], wj[NREF];
    calc_weights(rcn + (size_t)zi * NREF, cn[i], wi);
    calc_weights(rcn + (size_t)zj * NREF, cn[j], wj);
    const float* T = rc6 + (size_t)(zi * MAXZ + zj) * 25;
    float c6 = 0.0f;
#pragma unroll
    for (int a = 0; a < NREF; a++) {
        float s = 0.0f;
#pragma unroll
        for (int bb = 0; bb < NREF; bb++) s = fmaf(wj[bb], T[a * NREF + bb], s);
        c6 = fmaf(wi[a], s, c6);
    }
    float qq = 3.0f * r2r4[zi] * r2r4[zj];
    float rr = a1p[0] * sqrtf(qq) + a2p[0];
    float d2 = d * d;
    float d6 = d2 * d2 * d2;
    float d8 = d6 * d2;
    float rr2 = rr * rr;
    float rr6 = rr2 * rr2 * rr2;
    float rr8 = rr6 * rr2;
    float sw = switch_fn(d);
    float e = -0.5f * (s6p[0] * c6 / (d6 + rr6) + s8p[0] * qq * c6 / (d8 + rr8)) * sw;
    atomicAdd(&eout[i], e);
}

// ---------------------------------------------------------------------------
extern "C" void kernel_launch(void* const* d_in, const int* in_sizes, int n_in,
                              void* d_out, int out_size, void* d_ws, size_t ws_size,
                              hipStream_t stream) {
    const float* dist = (const float*)d_in[0];
    const float* rcov = (const float*)d_in[1];
    const float* rcn  = (const float*)d_in[2];
    const float* rc6  = (const float*)d_in[3];
    const float* r2r4 = (const float*)d_in[4];
    const float* s6p  = (const float*)d_in[5];
    const float* s8p  = (const float*)d_in[6];
    const float* a1p  = (const float*)d_in[7];
    const float* a2p  = (const float*)d_in[8];
    const int* Z    = (const int*)d_in[9];
    const int* idxi = (const int*)d_in[10];
    const int* idxj = (const int*)d_in[11];
    float* out = (float*)d_out;

    int n_pairs = in_sizes[0];
    int n_atoms = in_sizes[9];

    char* ws = (char*)d_ws;
    size_t o_bcount = 0;                                       // NB u32 (pad 4K)
    size_t o_rcovA  = 4096;
    size_t o_arec   = (o_rcovA + (size_t)n_atoms * 4 + 15) & ~(size_t)15;
    size_t o_rc6    = (o_arec + (size_t)n_atoms * 16 + 63) & ~(size_t)63;
    size_t o_recs   = (o_rc6 + (size_t)RC_TOTAL * 2 + 255) & ~(size_t)255;
    size_t need     = o_recs + ((size_t)NB << CAPSH) * 8;

    uint32_t* bcount = (uint32_t*)(ws + o_bcount);
    float* rcovA  = (float*)(ws + o_rcovA);
    uint4* arec_h = (uint4*)(ws + o_arec);
    u16*   rcpad  = (u16*)(ws + o_rc6);
    uint2* recs   = (uint2*)(ws + o_recs);

    if (ws_size >= need && n_atoms <= NB * BSZ && n_atoms <= 65536) {
        hipMemsetAsync(bcount, 0, NB * 4, stream);
        int chunk = (n_pairs + SBLOCKS - 1) / SBLOCKS;
        scatter_pairs<<<SBLOCKS, 1024, 0, stream>>>(dist, idxi, idxj, Z, rcov, rc6,
                                                    rcovA, rcpad, bcount, recs,
                                                    n_pairs, n_atoms, chunk);

        static int coop_ok = -1;
        if (coop_ok < 0) {
            int dev = 0, v = 0;
            hipGetDevice(&dev);
            hipDeviceGetAttribute(&v, hipDeviceAttributeCooperativeLaunch, dev);
            coop_ok = v ? 1 : 0;
        }
        bool fused = false;
        if (coop_ok) {
            const uint2* a_recs = recs; const uint32_t* a_bc = bcount;
            const float* a_rcovA = rcovA; const int* a_Z = Z;
            const float* a_rcn = rcn; const float* a_r2r4 = r2r4;
            uint4* a_arec = arec_h; const u16* a_rcpad = rcpad;
            const float* a_s6 = s6p; const float* a_s8 = s8p;
            const float* a_a1 = a1p; const float* a_a2 = a2p;
            float* a_out = out; int a_na = n_atoms;
            void* args[] = {(void*)&a_recs, (void*)&a_bc, (void*)&a_rcovA,
                            (void*)&a_Z, (void*)&a_rcn, (void*)&a_r2r4,
                            (void*)&a_arec, (void*)&a_rcpad, (void*)&a_s6,
                            (void*)&a_s8, (void*)&a_a1, (void*)&a_a2,
                            (void*)&a_out, (void*)&a_na};
            hipError_t e = hipLaunchCooperativeKernel((const void*)cn_energy_fused,
                                                      dim3(NB), dim3(256), args,
                                                      0, stream);
            if (e == hipSuccess) fused = true; else coop_ok = 0;
        }
        if (!fused) {
            cn_weights_bucket<<<NB, 256, 0, stream>>>(recs, bcount, rcovA, Z, rcn,
                                                      r2r4, arec_h, n_atoms);
            energy_bucket<<<NB, 256, 0, stream>>>(recs, bcount, arec_h, rcpad,
                                                  s6p, s8p, a1p, a2p, out, n_atoms);
        }
    } else {
        int pgrid = (n_pairs + 255) / 256;
        float* cn = (float*)(ws + o_rcovA);      // reuse slot as cn accumulator
        hipMemsetAsync(out, 0, (size_t)n_atoms * 4, stream);
        hipMemsetAsync(cn, 0, (size_t)n_atoms * 4, stream);
        pair_cn_slim<<<pgrid, 256, 0, stream>>>(dist, rcov, Z, idxi, idxj, cn, n_pairs);
        pair_energy_slim<<<pgrid, 256, 0, stream>>>(dist, Z, idxi, idxj, cn, rcn, r2r4,
                                                    rc6, s6p, s8p, a1p, a2p, out, n_pairs);
    }
}

// Round 5
// 139.028 us; speedup vs baseline: 2.0638x; 1.8733x over previous
//
#include <hip/hip_runtime.h>
#include <stdint.h>

// D3 dispersion on MI355X (gfx950). R22 = exact revert to R18 (best measured:
// 139.0us), the empirical optimum of this pipeline family.
// Pipeline: scatter (128x1024, tile=16K LDS bucket-sort -> rank-ordered burst
// writes; prologue fills rcovA+f16 rc6pad) -> cn+weights per 64-atom bucket
// (LDS accum, fused weight pack) -> energy per bucket (f16 16B arec gather +
// 64B tile gather, LDS accum). Zero global fp32 atomics.
// Ledger: R18 burst-write WIN (147.8->139.0, write-amp theory confirmed).
// R19 SBLOCKS=256+shfl-scan NEUTRAL (139.3; run halving re-created partial
// lines). R20 slim-hybrid REGRESSION (287us; 2M global fp32 atomics =117us
// pair_energy @8.8% HBM -> "zero global fp32 atomics" is load-bearing).
// R21 coop-fused cn+energy REGRESSION (260us; FETCH halved as predicted but
// kernel 4x slower -- fused/coop structure serialized: flat-pointer LDS-atomic
// suspicion + grid.sync lockstep). Falsified earlier: wave count (R9), coop
// fusion (R7), per-thread batching (R11), record packing (R13), SW pipe (R14),
// LDS sub-slots/fast-math (R15), block-count run-length (R16/R19).
// Harness floor: iteration = 54 dispatches, ~50 harness (~100us incl 45us
// 268MB poison fill @75% HBM peak); our 4 dispatches ~39us vs ~25us ideal.
// Reference semantics (R2-R5): fp32 storage; np reference is fp32 with FTZ in
// exp -> exceptional one-hot branch iff every masked gaussian arg < -87.33654.

typedef unsigned short u16;
#define MAXZ 95
#define NREF 5
#define EXC_CUT -87.33654f
#define NB    1024     // buckets
#define BSH   6        // log2 atoms per bucket
#define BSZ   64       // atoms per bucket
#define CAPSH 12       // bucket capacity 4096 (mean ~1865, sigma ~43)
#define SBLOCKS 128    // scatter blocks (proven optimum)
#define TILE  16384    // pairs staged+sorted per LDS tile (128 KB)
#define RC_TOTAL (MAXZ * MAXZ * 32)

__device__ __forceinline__ float h2f(u16 h) {
    union { _Float16 h; u16 u; } v; v.u = h; return (float)v.h;
}
__device__ __forceinline__ u16 f2h(float f) {
    union { _Float16 h; u16 u; } v; v.h = (_Float16)f; return v.u;
}

__device__ __forceinline__ float switch_fn(float d) {
    if (d < 10.0f) return 1.0f;
    float x = (12.0f - d) * 0.5f;
    return ((6.0f * x - 15.0f) * x + 10.0f) * x * x * x;
}

__device__ __forceinline__ void calc_weights(const float* __restrict__ rcn_z,
                                             float cni, float* __restrict__ w) {
    float r[NREF], arg[NREF];
    float rmax = -1e30f, marg = -1e30f;
#pragma unroll
    for (int a = 0; a < NREF; a++) {
        r[a] = rcn_z[a];
        rmax = fmaxf(rmax, r[a]);
        float dc = r[a] - cni;
        arg[a] = (-4.0f * dc) * dc;
        if (r[a] >= 0.0f) marg = fmaxf(marg, arg[a]);
    }
    if (marg < EXC_CUT) {
#pragma unroll
        for (int a = 0; a < NREF; a++) w[a] = (r[a] == rmax) ? 1.0f : 0.0f;
    } else {
        float g[NREF], norm = 0.0f;
#pragma unroll
        for (int a = 0; a < NREF; a++) {
            float e = (r[a] >= 0.0f) ? expf(arg[a]) : 0.0f;
            g[a] = e;
            norm += e;
        }
        float inv = 1.0f / fmaxf(norm, 1e-30f);
#pragma unroll
        for (int a = 0; a < NREF; a++) w[a] = g[a] * inv;
    }
}

// ---------------------------------------------------------------------------
// Scatter pairs into fixed-stride buckets; prologue fills rcovA + f16 rc6pad.
// Per 16K-pair tile: load once into regs -> LDS hist -> exclusive scan ->
// LDS bucket-sort -> rank-ordered burst write (consecutive lanes write
// consecutive addresses within each bucket run).
// Record: {d_fp32, j | il<<16}; bucket id rides in bits 22..31 while staged.
__global__ __launch_bounds__(1024) void scatter_pairs(const float* __restrict__ dist,
                                                      const int* __restrict__ idx_i,
                                                      const int* __restrict__ idx_j,
                                                      const int* __restrict__ Z,
                                                      const float* __restrict__ rcov,
                                                      const float* __restrict__ rc6,
                                                      float* __restrict__ rcovA,
                                                      u16* __restrict__ rc6pad,
                                                      uint32_t* __restrict__ bcount,
                                                      uint2* __restrict__ recs,
                                                      int n_pairs, int n_atoms,
                                                      int chunk) {
    __shared__ uint2 stage[TILE];          // 128 KB, bucket-sorted records
    __shared__ uint32_t hist[NB];          // per-tile bucket counts
    __shared__ uint32_t startb[NB];        // exclusive scan of hist
    __shared__ uint32_t cur[NB];           // scan scratch / scatter cursor
    __shared__ uint32_t res[NB];           // global base per bucket (this tile)

    int tid = (int)threadIdx.x;
    int g = blockIdx.x * 1024 + tid;
    int T = gridDim.x * 1024;
    for (int i = g; i < n_atoms; i += T) rcovA[i] = rcov[Z[i]];
    for (int id = g; id < RC_TOTAL; id += T) {
        int tile = id >> 5, slot = id & 31;
        rc6pad[id] = (slot < 25) ? f2h(rc6[(size_t)tile * 25 + slot]) : (u16)0;
    }

    int lo = blockIdx.x * chunk;
    int hi = min(lo + chunk, n_pairs);

    for (int t0 = lo; t0 < hi; t0 += TILE) {
        int tend = min(t0 + TILE, hi);
        hist[tid] = 0;
        __syncthreads();

        // load tile once (4-wide), filter d<12, histogram; hold recs in regs
        uint32_t rx[16], ry[16], vm = 0;
#pragma unroll
        for (int it = 0; it < 4; it++) {
            int q0 = t0 + tid * 4 + it * 4096;
            int m = (q0 < tend) ? min(4, tend - q0) : 0;
            float d4[4]; int i4[4], j4[4];
            if (m == 4) {
                float4 dv = *(const float4*)(dist + q0);
                int4 iv = *(const int4*)(idx_i + q0);
                int4 jv = *(const int4*)(idx_j + q0);
                d4[0] = dv.x; d4[1] = dv.y; d4[2] = dv.z; d4[3] = dv.w;
                i4[0] = iv.x; i4[1] = iv.y; i4[2] = iv.z; i4[3] = iv.w;
                j4[0] = jv.x; j4[1] = jv.y; j4[2] = jv.z; j4[3] = jv.w;
            } else {
                for (int s = 0; s < m; s++) {
                    d4[s] = dist[q0 + s]; i4[s] = idx_i[q0 + s]; j4[s] = idx_j[q0 + s];
                }
            }
#pragma unroll
            for (int s = 0; s < 4; s++) {
                int k = it * 4 + s;
                rx[k] = 0u; ry[k] = 0u;
                if (s < m && d4[s] < 12.0f) {
                    uint32_t i = (uint32_t)i4[s];
                    uint32_t b = i >> BSH;
                    rx[k] = __float_as_uint(d4[s]);
                    ry[k] = ((uint32_t)j4[s] & 0xFFFFu) |
                            ((i & (BSZ - 1u)) << 16) | (b << 22);
                    vm |= (1u << k);
                    atomicAdd(&hist[b], 1u);
                }
            }
        }
        __syncthreads();

        // exclusive scan of hist -> startb (Hillis-Steele over 1024 entries)
        cur[tid] = hist[tid];
        __syncthreads();
#pragma unroll
        for (int off = 1; off < NB; off <<= 1) {
            uint32_t v = (tid >= off) ? cur[tid - off] : 0u;
            __syncthreads();
            cur[tid] += v;
            __syncthreads();
        }
        startb[tid] = cur[tid] - hist[tid];
        // global reservation for this tile's runs
        uint32_t h = hist[tid];
        res[tid] = h ? atomicAdd(&bcount[tid], h) : 0u;
        cur[tid] = startb[tid];            // becomes scatter cursor
        __syncthreads();

        // bucket-sort records into LDS
#pragma unroll
        for (int k = 0; k < 16; k++) {
            if (vm & (1u << k)) {
                uint32_t b = ry[k] >> 22;
                uint32_t pos = atomicAdd(&cur[b], 1u);
                stage[pos] = make_uint2(rx[k], ry[k]);
            }
        }
        __syncthreads();

        // burst write: within each run, consecutive lanes -> consecutive addrs
        uint32_t total = startb[NB - 1] + hist[NB - 1];
        for (uint32_t t = (uint32_t)tid; t < total; t += 1024u) {
            uint2 r = stage[t];
            uint32_t b = r.y >> 22;
            uint32_t gpos = res[b] + (t - startb[b]);
            if (gpos < (1u << CAPSH))
                recs[((size_t)b << CAPSH) + gpos] =
                    make_uint2(r.x, r.y & 0x3FFFFFu);
        }
        __syncthreads();
    }
}

// ---------------------------------------------------------------------------
// CN + fused weights: one block per bucket, depth-3 rolling pipeline.
__global__ __launch_bounds__(256) void cn_weights_bucket(const uint2* __restrict__ recs,
                                                         const uint32_t* __restrict__ bcount,
                                                         const float* __restrict__ rcovA,
                                                         const int* __restrict__ Z,
                                                         const float* __restrict__ rcn,
                                                         const float* __restrict__ r2r4,
                                                         uint4* __restrict__ arec_h,
                                                         int n_atoms) {
    __shared__ float lrc[BSZ];
    __shared__ float acc[BSZ];
    int b = blockIdx.x;
    int base = b << BSH;
    if (threadIdx.x < BSZ) {
        int i = base + (int)threadIdx.x;
        lrc[threadIdx.x] = (i < n_atoms) ? rcovA[i] : 0.0f;
        acc[threadIdx.x] = 0.0f;
    }
    __syncthreads();
    uint32_t n = min(bcount[b], 1u << CAPSH);
    const uint2* r0 = recs + ((size_t)b << CAPSH);
    if (n) {
        uint32_t nm1 = n - 1;
        uint32_t k = threadIdx.x;
        uint2 recA = r0[min(k, nm1)];
        uint2 recB = r0[min(k + 256, nm1)];
        float rjA = rcovA[recA.y & 0xFFFF];
        for (; k < n; k += 256) {
            uint2 recC = r0[min(k + 512, nm1)];
            float rjB = rcovA[recB.y & 0xFFFF];
            float d = __uint_as_float(recA.x);
            int il = (recA.y >> 16) & (BSZ - 1);
            float rij = lrc[il] + rjA;
            float sw = switch_fn(d);
            atomicAdd(&acc[il], sw / (1.0f + expf(-16.0f * (rij / d - 1.0f))));
            recA = recB; recB = recC; rjA = rjB;
        }
    }
    __syncthreads();
    if (threadIdx.x < BSZ) {
        int i = base + (int)threadIdx.x;
        if (i < n_atoms) {
            int z = Z[i];
            float w[NREF];
            calc_weights(rcn + (size_t)z * NREF, acc[threadIdx.x], w);
            uint4 pk;
            pk.x = (uint32_t)f2h(w[0]) | ((uint32_t)f2h(w[1]) << 16);
            pk.y = (uint32_t)f2h(w[2]) | ((uint32_t)f2h(w[3]) << 16);
            pk.z = (uint32_t)f2h(w[4]) | ((uint32_t)f2h(r2r4[z]) << 16);
            pk.w = (uint32_t)z;
            arec_h[i] = pk;
        }
    }
}

// ---------------------------------------------------------------------------
// Energy: one block per bucket, depth-3 rolling pipeline.
__global__ __launch_bounds__(256) void energy_bucket(const uint2* __restrict__ recs,
                                                     const uint32_t* __restrict__ bcount,
                                                     const uint4* __restrict__ arec_h,
                                                     const u16* __restrict__ rc6pad,
                                                     const float* __restrict__ s6p,
                                                     const float* __restrict__ s8p,
                                                     const float* __restrict__ a1p,
                                                     const float* __restrict__ a2p,
                                                     float* __restrict__ eout,
                                                     int n_atoms) {
    __shared__ float4 la0[BSZ];
    __shared__ float4 la1[BSZ];
    __shared__ float  acc[BSZ];
    int b = blockIdx.x;
    int base = b << BSH;
    if (threadIdx.x < BSZ) {
        int i = min(base + (int)threadIdx.x, n_atoms - 1);
        uint4 pk = arec_h[i];
        la0[threadIdx.x] = make_float4(h2f(pk.x & 0xFFFFu), h2f(pk.x >> 16),
                                       h2f(pk.y & 0xFFFFu), h2f(pk.y >> 16));
        la1[threadIdx.x] = make_float4(h2f(pk.z & 0xFFFFu), h2f(pk.z >> 16),
                                       __int_as_float((int)pk.w), 0.0f);
        acc[threadIdx.x] = 0.0f;
    }
    __syncthreads();
    float s6 = s6p[0], s8 = s8p[0], a1 = a1p[0], a2 = a2p[0];
    uint32_t n = min(bcount[b], 1u << CAPSH);
    const uint2* r0 = recs + ((size_t)b << CAPSH);
    if (n) {
        uint32_t nm1 = n - 1;
        uint32_t k = threadIdx.x;
        uint2 recA = r0[min(k, nm1)];
        uint2 recB = r0[min(k + 256, nm1)];
        uint4 pjA = arec_h[recA.y & 0xFFFFu];
        for (; k < n; k += 256) {
            uint2 recC = r0[min(k + 512, nm1)];
            uint4 pjB = arec_h[recB.y & 0xFFFFu];

            int il = (recA.y >> 16) & (BSZ - 1);
            float4 ai1 = la1[il];
            int zi = __float_as_int(ai1.z);
            int zj = (int)pjA.w;
            const uint4* T4 = (const uint4*)(rc6pad + (size_t)(zi * MAXZ + zj) * 32);
            uint4 t0 = T4[0], t1 = T4[1], t2 = T4[2];
            uint32_t t3 = ((const uint32_t*)T4)[12];

            float d = __uint_as_float(recA.x);
            float4 ai0 = la0[il];
            float wi[NREF] = {ai0.x, ai0.y, ai0.z, ai0.w, ai1.x};
            float wj[NREF] = {h2f(pjA.x & 0xFFFFu), h2f(pjA.x >> 16),
                              h2f(pjA.y & 0xFFFFu), h2f(pjA.y >> 16),
                              h2f(pjA.z & 0xFFFFu)};
            float r2r4j = h2f(pjA.z >> 16);

            float tt[25];
            uint32_t tw[12] = {t0.x, t0.y, t0.z, t0.w, t1.x, t1.y, t1.z, t1.w,
                               t2.x, t2.y, t2.z, t2.w};
#pragma unroll
            for (int k2 = 0; k2 < 12; k2++) {
                tt[2 * k2]     = h2f((u16)(tw[k2] & 0xFFFFu));
                tt[2 * k2 + 1] = h2f((u16)(tw[k2] >> 16));
            }
            tt[24] = h2f((u16)(t3 & 0xFFFFu));

            float c6 = 0.0f;
#pragma unroll
            for (int a = 0; a < NREF; a++) {
                float ss = 0.0f;
#pragma unroll
                for (int bb = 0; bb < NREF; bb++) ss = fmaf(wj[bb], tt[a * NREF + bb], ss);
                c6 = fmaf(wi[a], ss, c6);
            }

            float qq = 3.0f * ai1.y * r2r4j;
            float rr = a1 * sqrtf(qq) + a2;
            float d2 = d * d;
            float d6 = d2 * d2 * d2;
            float d8 = d6 * d2;
            float rr2 = rr * rr;
            float rr6 = rr2 * rr2 * rr2;
            float rr8 = rr6 * rr2;
            float sw = switch_fn(d);

            float e = -0.5f * (s6 * c6 / (d6 + rr6) + s8 * qq * c6 / (d8 + rr8)) * sw;
            atomicAdd(&acc[il], e);

            recA = recB; recB = recC; pjA = pjB;
        }
    }
    __syncthreads();
    if (threadIdx.x < BSZ) {
        int i = base + (int)threadIdx.x;
        if (i < n_atoms) eout[i] = acc[threadIdx.x];
    }
}

// ---------------------------------------------------------------------------
// Slim fallback (small workspace): R5-style global-atomic fp32 path.
__global__ __launch_bounds__(256) void pair_cn_slim(const float* __restrict__ dist,
                                                    const float* __restrict__ rcov,
                                                    const int* __restrict__ Z,
                                                    const int* __restrict__ idx_i,
                                                    const int* __restrict__ idx_j,
                                                    float* __restrict__ cn,
                                                    int n_pairs) {
    int p = blockIdx.x * blockDim.x + threadIdx.x;
    if (p >= n_pairs) return;
    float d = dist[p];
    if (d >= 12.0f) return;
    float rij = rcov[Z[idx_i[p]]] + rcov[Z[idx_j[p]]];
    float sw = switch_fn(d);
    atomicAdd(&cn[idx_i[p]], sw / (1.0f + expf(-16.0f * (rij / d - 1.0f))));
}

__global__ __launch_bounds__(256) void pair_energy_slim(const float* __restrict__ dist,
                                                        const int* __restrict__ Z,
                                                        const int* __restrict__ idx_i,
                                                        const int* __restrict__ idx_j,
                                                        const float* __restrict__ cn,
                                                        const float* __restrict__ rcn,
                                                        const float* __restrict__ r2r4,
                                                        const float* __restrict__ rc6,
                                                        const float* __restrict__ s6p,
                                                        const float* __restrict__ s8p,
                                                        const float* __restrict__ a1p,
                                                        const float* __restrict__ a2p,
                                                        float* __restrict__ eout,
                                                        int n_pairs) {
    int p = blockIdx.x * blockDim.x + threadIdx.x;
    if (p >= n_pairs) return;
    float d = dist[p];
    if (d >= 12.0f) return;
    int i = idx_i[p], j = idx_j[p];
    int zi = Z[i], zj = Z[j];
    float wi[NREF], wj[NREF];
    calc_weights(rcn + (size_t)zi * NREF, cn[i], wi);
    calc_weights(rcn + (size_t)zj * NREF, cn[j], wj);
    const float* T = rc6 + (size_t)(zi * MAXZ + zj) * 25;
    float c6 = 0.0f;
#pragma unroll
    for (int a = 0; a < NREF; a++) {
        float s = 0.0f;
#pragma unroll
        for (int bb = 0; bb < NREF; bb++) s = fmaf(wj[bb], T[a * NREF + bb], s);
        c6 = fmaf(wi[a], s, c6);
    }
    float qq = 3.0f * r2r4[zi] * r2r4[zj];
    float rr = a1p[0] * sqrtf(qq) + a2p[0];
    float d2 = d * d;
    float d6 = d2 * d2 * d2;
    float d8 = d6 * d2;
    float rr2 = rr * rr;
    float rr6 = rr2 * rr2 * rr2;
    float rr8 = rr6 * rr2;
    float sw = switch_fn(d);
    float e = -0.5f * (s6p[0] * c6 / (d6 + rr6) + s8p[0] * qq * c6 / (d8 + rr8)) * sw;
    atomicAdd(&eout[i], e);
}

// ---------------------------------------------------------------------------
extern "C" void kernel_launch(void* const* d_in, const int* in_sizes, int n_in,
                              void* d_out, int out_size, void* d_ws, size_t ws_size,
                              hipStream_t stream) {
    const float* dist = (const float*)d_in[0];
    const float* rcov = (const float*)d_in[1];
    const float* rcn  = (const float*)d_in[2];
    const float* rc6  = (const float*)d_in[3];
    const float* r2r4 = (const float*)d_in[4];
    const float* s6p  = (const float*)d_in[5];
    const float* s8p  = (const float*)d_in[6];
    const float* a1p  = (const float*)d_in[7];
    const float* a2p  = (const float*)d_in[8];
    const int* Z    = (const int*)d_in[9];
    const int* idxi = (const int*)d_in[10];
    const int* idxj = (const int*)d_in[11];
    float* out = (float*)d_out;

    int n_pairs = in_sizes[0];
    int n_atoms = in_sizes[9];

    char* ws = (char*)d_ws;
    size_t o_bcount = 0;                                       // NB u32 (pad 4K)
    size_t o_rcovA  = 4096;
    size_t o_arec   = (o_rcovA + (size_t)n_atoms * 4 + 15) & ~(size_t)15;
    size_t o_rc6    = (o_arec + (size_t)n_atoms * 16 + 63) & ~(size_t)63;
    size_t o_recs   = (o_rc6 + (size_t)RC_TOTAL * 2 + 255) & ~(size_t)255;
    size_t need     = o_recs + ((size_t)NB << CAPSH) * 8;

    uint32_t* bcount = (uint32_t*)(ws + o_bcount);
    float* rcovA  = (float*)(ws + o_rcovA);
    uint4* arec_h = (uint4*)(ws + o_arec);
    u16*   rcpad  = (u16*)(ws + o_rc6);
    uint2* recs   = (uint2*)(ws + o_recs);

    if (ws_size >= need && n_atoms <= NB * BSZ && n_atoms <= 65536) {
        hipMemsetAsync(bcount, 0, NB * 4, stream);
        int chunk = (n_pairs + SBLOCKS - 1) / SBLOCKS;
        scatter_pairs<<<SBLOCKS, 1024, 0, stream>>>(dist, idxi, idxj, Z, rcov, rc6,
                                                    rcovA, rcpad, bcount, recs,
                                                    n_pairs, n_atoms, chunk);
        cn_weights_bucket<<<NB, 256, 0, stream>>>(recs, bcount, rcovA, Z, rcn, r2r4,
                                                  arec_h, n_atoms);
        energy_bucket<<<NB, 256, 0, stream>>>(recs, bcount, arec_h, rcpad,
                                              s6p, s8p, a1p, a2p, out, n_atoms);
    } else {
        int pgrid = (n_pairs + 255) / 256;
        float* cn = (float*)(ws + o_rcovA);      // reuse slot as cn accumulator
        hipMemsetAsync(out, 0, (size_t)n_atoms * 4, stream);
        hipMemsetAsync(cn, 0, (size_t)n_atoms * 4, stream);
        pair_cn_slim<<<pgrid, 256, 0, stream>>>(dist, rcov, Z, idxi, idxj, cn, n_pairs);
        pair_energy_slim<<<pgrid, 256, 0, stream>>>(dist, Z, idxi, idxj, cn, rcn, r2r4,
                                                    rc6, s6p, s8p, a1p, a2p, out, n_pairs);
    }
}